// Round 1
// baseline (8046.141 us; speedup 1.0000x reference)
//
#include <hip/hip_runtime.h>

#define GV 1024
#define BATCH 128
#define M_TOT (BATCH * GV)   // 131072 rows
#define CHEB_K 5

// ---------------- transpose x [B,3,V] -> h [M,3] (c fastest) ----------------
__global__ void k_transpose_x(const float* __restrict__ x, float* __restrict__ h) {
    int idx = blockIdx.x * 256 + threadIdx.x;
    if (idx >= M_TOT * 3) return;
    int c = idx % 3;
    int m = idx / 3;
    int v = m & (GV - 1);
    int b = m / GV;
    h[idx] = x[((size_t)b * 3 + c) * GV + v];
}

// ---------------- Chebyshev sparse apply (4-point grid stencil) -------------
// P[idx] = alpha * sum_{v in N(u)} L[u,v] * Xc[b,v,c] - (useP ? P[idx] : 0)
// In-place over P is safe: each idx is read+written by exactly one thread,
// and neighbor reads come only from Xc (a different buffer).
__global__ void k_cheb_apply(const float* __restrict__ Xc, const float* __restrict__ L,
                             float* __restrict__ P, int C, int total,
                             float alpha, int useP) {
    int idx = blockIdx.x * 256 + threadIdx.x;
    if (idx >= total) return;
    int c = idx % C;
    int m = idx / C;
    int u = m & (GV - 1);
    int b = m / GV;
    int gi = u >> 5, gj = u & 31;
    const float* Lrow = L + (size_t)u * GV;
    const float* Xb = Xc + (size_t)b * GV * C;
    float s = 0.f;
    if (gi > 0)  s += Lrow[u - 32] * Xb[(size_t)(u - 32) * C + c];
    if (gi < 31) s += Lrow[u + 32] * Xb[(size_t)(u + 32) * C + c];
    if (gj > 0)  s += Lrow[u - 1]  * Xb[(size_t)(u - 1) * C + c];
    if (gj < 31) s += Lrow[u + 1]  * Xb[(size_t)(u + 1) * C + c];
    float prev = useP ? P[idx] : 0.f;
    P[idx] = alpha * s - prev;
}

// ---------------- tall-skinny fp32 GEMM with accumulate --------------------
// Y[M,N] (+)= A[M,Kd] * B'[Kd,N], B'(c,o) = W[o*wstride + c*CHEB_K + kOff]
#define BM 64
#define BN 32
#define BKT 16

__global__ void k_gemm(const float* __restrict__ A, const float* __restrict__ W,
                       float* __restrict__ Y, int N, int Kd, int wstride, int kOff,
                       int accum) {
    __shared__ float As[BKT][BM + 4];   // +4 pad: 2-way-free LDS banks, keeps 16B align
    __shared__ float Bs[BKT][BN + 4];
    int tid = threadIdx.x;
    int tx = tid & 15;       // col group 0..15
    int ty = tid >> 4;       // row group 0..15
    size_t bm = (size_t)blockIdx.x * BM;
    int bn = blockIdx.y * BN;
    float acc[4][2] = {};
    for (int k0 = 0; k0 < Kd; k0 += BKT) {
        #pragma unroll
        for (int jj = 0; jj < 4; ++jj) {         // A tile: 64 rows x 16 k
            int r = ty + jj * 16;
            float va = 0.f;
            if (k0 + tx < Kd) va = A[(bm + r) * (size_t)Kd + k0 + tx];
            As[tx][r] = va;
        }
        #pragma unroll
        for (int jj = 0; jj < 2; ++jj) {         // B tile: 16 k x 32 n
            int n = ty + jj * 16;
            float vb = 0.f;
            if (k0 + tx < Kd) vb = W[(size_t)(bn + n) * wstride + (k0 + tx) * CHEB_K + kOff];
            Bs[tx][n] = vb;
        }
        __syncthreads();
        #pragma unroll
        for (int kk = 0; kk < BKT; ++kk) {
            float4 a4 = *(const float4*)&As[kk][ty * 4];   // broadcast across tx
            float b0 = Bs[kk][tx * 2], b1 = Bs[kk][tx * 2 + 1];
            acc[0][0] += a4.x * b0; acc[0][1] += a4.x * b1;
            acc[1][0] += a4.y * b0; acc[1][1] += a4.y * b1;
            acc[2][0] += a4.z * b0; acc[2][1] += a4.z * b1;
            acc[3][0] += a4.w * b0; acc[3][1] += a4.w * b1;
        }
        __syncthreads();
    }
    #pragma unroll
    for (int r = 0; r < 4; ++r) {
        size_t row = bm + ty * 4 + r;
        size_t base = row * (size_t)N + bn + tx * 2;
        if (accum) {
            Y[base]     += acc[r][0];
            Y[base + 1] += acc[r][1];
        } else {
            Y[base]     = acc[r][0];
            Y[base + 1] = acc[r][1];
        }
    }
}

// ---------------- BN: per-channel sum / sumsq over M rows ------------------
__global__ void k_bn_stats(const float* __restrict__ Y, float* __restrict__ stats,
                           int N, int rowsPerBlock) {
    int rpi = 256 / N;               // 2 for N=96, 1 for N=192
    int c = threadIdx.x % N;
    int r = threadIdx.x / N;
    if (r >= rpi) return;
    int m0 = blockIdx.x * rowsPerBlock;
    float s = 0.f, s2 = 0.f;
    for (int m = m0 + r; m < m0 + rowsPerBlock; m += rpi) {
        float v = Y[(size_t)m * N + c];      // threads cover contiguous channels: coalesced
        s += v; s2 += v * v;
    }
    atomicAdd(&stats[c], s);
    atomicAdd(&stats[N + c], s2);
}

// ---------------- BN finalize + ReLU, in-place over Y ----------------------
__global__ void k_bn_relu(float* __restrict__ Y, const float* __restrict__ stats,
                          const float* __restrict__ g, const float* __restrict__ bb,
                          int N, int total) {
    int idx = blockIdx.x * 256 + threadIdx.x;
    if (idx >= total) return;
    int c = idx % N;
    const float inv = 1.f / (float)M_TOT;
    float mean = stats[c] * inv;
    float var = stats[N + c] * inv - mean * mean;
    float rs = rsqrtf(var + 1e-5f);
    float v = (Y[idx] - mean) * rs * g[c] + bb[c];
    Y[idx] = v > 0.f ? v : 0.f;
}

// ---------------- h [M,96] -> ht [B,96,V] for classifier -------------------
__global__ void k_transpose_h(const float* __restrict__ h, float* __restrict__ ht) {
    int idx = blockIdx.x * 256 + threadIdx.x;
    if (idx >= BATCH * 96 * GV) return;
    int v = idx & (GV - 1);
    int c = (idx / GV) % 96;
    int b = idx / (96 * GV);
    ht[idx] = h[((size_t)b * GV + v) * 96 + c];
}

// ---------------- classifier: out[b,o] = <ht[b,:], w[o,:]> + bias[o] -------
__global__ void k_classifier(const float* __restrict__ ht, const float* __restrict__ w,
                             const float* __restrict__ bias, float* __restrict__ out) {
    int b = blockIdx.x, o = blockIdx.y;
    const float4* hb = (const float4*)(ht + (size_t)b * 96 * GV);
    const float4* wo = (const float4*)(w + (size_t)o * 96 * GV);
    float acc = 0.f;
    for (int f = threadIdx.x; f < 96 * GV / 4; f += 256) {
        float4 a = hb[f], c4 = wo[f];
        acc += a.x * c4.x + a.y * c4.y + a.z * c4.z + a.w * c4.w;
    }
    #pragma unroll
    for (int off = 32; off > 0; off >>= 1) acc += __shfl_down(acc, off, 64);
    __shared__ float red[4];
    int lane = threadIdx.x & 63, wv = threadIdx.x >> 6;
    if (lane == 0) red[wv] = acc;
    __syncthreads();
    if (threadIdx.x == 0) out[b * 10 + o] = red[0] + red[1] + red[2] + red[3] + bias[o];
}

extern "C" void kernel_launch(void* const* d_in, const int* in_sizes, int n_in,
                              void* d_out, int out_size, void* d_ws, size_t ws_size,
                              hipStream_t stream) {
    const float* x = (const float*)d_in[0];
    const float* L = (const float*)d_in[1];
    const float* wts[7]; const float* gs[7]; const float* bs[7];
    for (int i = 0; i < 7; ++i) {        // setup_inputs dict order: x, L, (w,g,b)*7, clf_w, clf_b
        wts[i] = (const float*)d_in[2 + 3 * i];
        gs[i]  = (const float*)d_in[3 + 3 * i];
        bs[i]  = (const float*)d_in[4 + 3 * i];
    }
    const float* clfw = (const float*)d_in[23];
    const float* clfb = (const float*)d_in[24];
    float* out = (float*)d_out;

    const int fin[7]  = {3, 96, 96, 96, 192, 192, 192};
    const int fout[7] = {96, 96, 96, 192, 192, 192, 96};

    const size_t BIG = (size_t)M_TOT * 192;          // floats per big buffer
    float* ws = (float*)d_ws;
    size_t availF = ws_size / sizeof(float);
    // choose recursion-scratch chunking so total footprint fits ws (deterministic
    // in ws_size -> identical work every call -> graph-capture safe)
    int nch = 1;
    while (nch < 8 && 2 * BIG + 384 + BIG / nch > availF) nch <<= 1;
    float* bufA  = ws;                    // activation / T ping buffer
    float* bufB  = ws + BIG;              // y / next activation buffer
    float* stats = ws + 2 * BIG;          // 2*192 floats
    float* tcb   = ws + 2 * BIG + 384;    // T pong buffer (chunked)
    int Mc = M_TOT / nch;                 // multiple of 1024 (batch-aligned) for nch<=8

    // x -> bufA as [M,3]
    hipLaunchKernelGGL(k_transpose_x, dim3((M_TOT * 3 + 255) / 256), dim3(256), 0, stream,
                       x, bufA);

    float* cur = bufA;   // layer input [M, fin]
    float* oth = bufB;   // layer output y [M, fout]
    for (int li = 0; li < 7; ++li) {
        int Ci = fin[li], Co = fout[li];
        int wstride = CHEB_K * Ci;
        float* yb = oth;
        for (int ch = 0; ch < nch; ++ch) {
            size_t ro = (size_t)ch * Mc;
            float* hc = cur + ro * Ci;          // T0 (destroyed by T2/T4 in-place)
            float* yc = yb + ro * Co;
            dim3 gg(Mc / BM, Co / BN);
            int totalC = Mc * Ci;
            dim3 ga((totalC + 255) / 256);
            // k=0 : y = T0 @ W0
            hipLaunchKernelGGL(k_gemm, gg, dim3(256), 0, stream, hc, wts[li], yc, Co, Ci, wstride, 0, 0);
            // T1 = L T0 -> tcb
            hipLaunchKernelGGL(k_cheb_apply, ga, dim3(256), 0, stream, hc, L, tcb, Ci, totalC, 1.f, 0);
            hipLaunchKernelGGL(k_gemm, gg, dim3(256), 0, stream, tcb, wts[li], yc, Co, Ci, wstride, 1, 1);
            // T2 = 2 L T1 - T0 -> hc
            hipLaunchKernelGGL(k_cheb_apply, ga, dim3(256), 0, stream, tcb, L, hc, Ci, totalC, 2.f, 1);
            hipLaunchKernelGGL(k_gemm, gg, dim3(256), 0, stream, hc, wts[li], yc, Co, Ci, wstride, 2, 1);
            // T3 = 2 L T2 - T1 -> tcb
            hipLaunchKernelGGL(k_cheb_apply, ga, dim3(256), 0, stream, hc, L, tcb, Ci, totalC, 2.f, 1);
            hipLaunchKernelGGL(k_gemm, gg, dim3(256), 0, stream, tcb, wts[li], yc, Co, Ci, wstride, 3, 1);
            // T4 = 2 L T3 - T2 -> hc
            hipLaunchKernelGGL(k_cheb_apply, ga, dim3(256), 0, stream, tcb, L, hc, Ci, totalC, 2.f, 1);
            hipLaunchKernelGGL(k_gemm, gg, dim3(256), 0, stream, hc, wts[li], yc, Co, Ci, wstride, 4, 1);
        }
        // BatchNorm (batch stats) + ReLU, in-place on yb
        hipMemsetAsync(stats, 0, 384 * sizeof(float), stream);
        hipLaunchKernelGGL(k_bn_stats, dim3(256), dim3(256), 0, stream, yb, stats, Co, M_TOT / 256);
        int totalY = M_TOT * Co;
        hipLaunchKernelGGL(k_bn_relu, dim3((totalY + 255) / 256), dim3(256), 0, stream,
                           yb, stats, gs[li], bs[li], Co, totalY);
        float* t = cur; cur = yb; oth = t;      // yb becomes next layer input
    }
    // classifier: needs torch view [B, C*V] (v fastest) -> transpose into oth
    hipLaunchKernelGGL(k_transpose_h, dim3((BATCH * 96 * GV + 255) / 256), dim3(256), 0, stream,
                       cur, oth);
    hipLaunchKernelGGL(k_classifier, dim3(BATCH, 10), dim3(256), 0, stream, oth, clfw, clfb, out);
}

// Round 2
// 3595.546 us; speedup vs baseline: 2.2378x; 2.2378x over previous
//
#include <hip/hip_runtime.h>
#include <hip/hip_bf16.h>

#define GV 1024
#define BATCH 128
#define M_TOT (BATCH * GV)   // 131072 rows
#define CHEB_K 5

typedef __bf16 bf16x8 __attribute__((ext_vector_type(8)));
typedef float  f32x4  __attribute__((ext_vector_type(4)));

// ---------------------------------------------------------------------------
// W [N, Ci*5] fp32 (f = c*5+k, torch order)  ->  Wb [N, KdPad] bf16 (f' = k*Ci+c)
__global__ void k_convw(const float* __restrict__ W, __hip_bfloat16* __restrict__ Wb,
                        int Ci, int N, int KdPad) {
    int idx = blockIdx.x * 256 + threadIdx.x;
    if (idx >= N * KdPad) return;
    int o = idx / KdPad, f = idx % KdPad;
    float v = 0.f;
    if (f < CHEB_K * Ci) {
        int k = f / Ci, c = f % Ci;
        v = W[(size_t)o * CHEB_K * Ci + c * CHEB_K + k];
    }
    Wb[idx] = __float2bfloat16(v);
}

// ---------------------------------------------------------------------------
// Fused: (optional BN+ReLU on load) -> Chebyshev recursion T0..T4 in LDS over
// one batch-element's full 32x32 grid, channel chunk CC -> write F bf16.
// Recursion kept in degree-scaled space S = D^{-1/2} T so stencil weights are
// exactly 1/deg (no per-neighbor transcendental): S_1 = -invdeg * sum_N S_0,
// S_k = -2*invdeg*sum_N S_{k-1} - S_{k-2};  T_k = sqrt(deg) * S_k.
// F layout: row m (chunk-local), col f = k*Cin + c  (c-contiguous writes).
__global__ __launch_bounds__(512, 1)
void k_cheb_expand(const float* __restrict__ X, const float* __restrict__ stats,
                   const float* __restrict__ g, const float* __restrict__ bb,
                   __hip_bfloat16* __restrict__ F, int Cin, int CC, int KdPad,
                   int useBN, int srcBCV, int bOff) {
    __shared__ float T[3][8192];    // 96 KB (CC <= 8)
    __shared__ float rdvs[1024];    // sqrt(deg) unscale factors
    int tid = threadIdx.x;
    int b = blockIdx.y + bOff;          // global batch index
    int c0 = blockIdx.x * CC;
    for (int u = tid; u < 1024; u += 512) {
        int gi = u >> 5, gj = u & 31;
        int deg = (gi > 0) + (gi < 31) + (gj > 0) + (gj < 31);
        rdvs[u] = sqrtf((float)deg);
    }
    const int NV = 1024 * CC;
    const float invM = 1.0f / (float)M_TOT;
    size_t mBase = ((size_t)b) << 10;
    size_t fBase = ((size_t)blockIdx.y) << 10;   // F rows are chunk-local
    // ---- load T0 (apply BN+ReLU of previous layer if requested) ----
    for (int i = tid; i < NV; i += 512) {
        int u = i / CC, c = i - u * CC;
        int cg = c0 + c;
        float v = srcBCV ? X[((size_t)b * Cin + cg) * GV + u]
                         : X[(mBase + u) * Cin + cg];
        if (useBN) {
            float mean = stats[cg] * invM;
            float var  = stats[Cin + cg] * invM - mean * mean;
            float vv = (v - mean) * rsqrtf(var + 1e-5f) * g[cg] + bb[cg];
            v = vv > 0.f ? vv : 0.f;
        }
        F[(fBase + u) * KdPad + cg] = __float2bfloat16(v);
        int gi = u >> 5, gj = u & 31;
        int deg = (gi > 0) + (gi < 31) + (gj > 0) + (gj < 31);
        T[0][i] = v * rsqrtf((float)deg);        // scaled S0
    }
    __syncthreads();
    // ---- recursion k = 1..4 ----
    for (int k = 1; k < CHEB_K; ++k) {
        const float* src = T[(k - 1) % 3];
        const float* old = T[(k + 1) % 3];       // == (k-2) mod 3
        float* dst = T[k % 3];
        for (int i = tid; i < NV; i += 512) {
            int u = i / CC, c = i - u * CC;
            int gi = u >> 5, gj = u & 31;
            float s = 0.f;
            if (gi > 0)  s += src[i - 32 * CC];
            if (gi < 31) s += src[i + 32 * CC];
            if (gj > 0)  s += src[i - CC];
            if (gj < 31) s += src[i + CC];
            int deg = (gi > 0) + (gi < 31) + (gj > 0) + (gj < 31);
            float invdeg = (deg == 4) ? 0.25f : (deg == 3 ? (1.f / 3.f) : 0.5f);
            float val = (k == 1) ? (-s * invdeg) : (-2.f * invdeg * s - old[i]);
            dst[i] = val;
            F[(fBase + u) * KdPad + k * Cin + c0 + c] = __float2bfloat16(val * rdvs[u]);
        }
        __syncthreads();
    }
    // ---- zero-pad (layer 0: Kd=15 -> KdPad=32); only chunk 0 pads ----
    int pad0 = CHEB_K * Cin;
    if (pad0 < KdPad && blockIdx.x == 0) {
        int W2 = KdPad - pad0;
        for (int i = tid; i < 1024 * W2; i += 512) {
            int u = i / W2, f = i - (i / W2) * W2;
            F[(fBase + u) * KdPad + pad0 + f] = __float2bfloat16(0.f);
        }
    }
}

// ---------------------------------------------------------------------------
// bf16 MFMA GEMM: Y[M_loc, N] = F[M_loc, KdPad] @ Wb[N, KdPad]^T   (fp32 out)
// + fused per-channel sum/sumsq accumulation into stats (for next-layer BN).
// Block = 256 thr = 4 waves; wave owns 32 rows (2 m-tiles), all N columns.
// Fragments loaded straight from global (A: HBM stream, B: L2-resident).
template<int NT>
__global__ __launch_bounds__(256, 2)
void k_gemm_bf16(const __hip_bfloat16* __restrict__ A, const __hip_bfloat16* __restrict__ Bw,
                 float* __restrict__ Y, float* __restrict__ stats, int KdPad) {
    constexpr int N = NT * 16;
    __shared__ float ls[2 * N];
    int tid = threadIdx.x;
    for (int t = tid; t < 2 * N; t += 256) ls[t] = 0.f;
    __syncthreads();
    int lane = tid & 63, wv = tid >> 6;
    int col = lane & 15, quad = lane >> 4;
    size_t m0 = (size_t)blockIdx.x * 128 + wv * 32;
    f32x4 acc[2][NT];
    #pragma unroll
    for (int t = 0; t < 2; ++t)
        #pragma unroll
        for (int n = 0; n < NT; ++n) acc[t][n] = (f32x4){0.f, 0.f, 0.f, 0.f};
    const __hip_bfloat16* Ap0 = A + (m0 + col) * (size_t)KdPad + quad * 8;
    const __hip_bfloat16* Ap1 = Ap0 + 16 * (size_t)KdPad;
    const __hip_bfloat16* Bp  = Bw + (size_t)col * KdPad + quad * 8;
    for (int k0 = 0; k0 < KdPad; k0 += 32) {
        bf16x8 a0 = *(const bf16x8*)(Ap0 + k0);
        bf16x8 a1 = *(const bf16x8*)(Ap1 + k0);
        #pragma unroll
        for (int n = 0; n < NT; ++n) {
            bf16x8 bf = *(const bf16x8*)(Bp + (size_t)(n * 16) * KdPad + k0);
            acc[0][n] = __builtin_amdgcn_mfma_f32_16x16x32_bf16(a0, bf, acc[0][n], 0, 0, 0);
            acc[1][n] = __builtin_amdgcn_mfma_f32_16x16x32_bf16(a1, bf, acc[1][n], 0, 0, 0);
        }
    }
    // epilogue: store Y + per-channel partial stats
    #pragma unroll
    for (int t = 0; t < 2; ++t) {
        #pragma unroll
        for (int n = 0; n < NT; ++n) {
            size_t r0 = m0 + t * 16 + quad * 4;
            int cg = n * 16 + col;
            float s = 0.f, s2 = 0.f;
            #pragma unroll
            for (int r = 0; r < 4; ++r) {
                float v = acc[t][n][r];
                Y[(r0 + r) * N + cg] = v;
                s += v; s2 += v * v;
            }
            s  += __shfl_xor(s, 16, 64);  s  += __shfl_xor(s, 32, 64);
            s2 += __shfl_xor(s2, 16, 64); s2 += __shfl_xor(s2, 32, 64);
            if (quad == 0) { atomicAdd(&ls[cg], s); atomicAdd(&ls[N + cg], s2); }
        }
    }
    __syncthreads();
    for (int t = tid; t < 2 * N; t += 256) atomicAdd(&stats[t], ls[t]);
}

// ---------------------------------------------------------------------------
// final BN+ReLU fused with transpose: h [M,96] -> ht [B,96,V]
__global__ void k_bn_transpose_h(const float* __restrict__ h, const float* __restrict__ stats,
                                 const float* __restrict__ g, const float* __restrict__ bb,
                                 float* __restrict__ ht) {
    int idx = blockIdx.x * 256 + threadIdx.x;
    if (idx >= BATCH * 96 * GV) return;
    int v = idx & (GV - 1);
    int c = (idx / GV) % 96;
    int b = idx / (96 * GV);
    const float invM = 1.0f / (float)M_TOT;
    float mean = stats[c] * invM;
    float var  = stats[96 + c] * invM - mean * mean;
    float x = (h[((size_t)b * GV + v) * 96 + c] - mean) * rsqrtf(var + 1e-5f) * g[c] + bb[c];
    ht[idx] = x > 0.f ? x : 0.f;
}

// ---------------------------------------------------------------------------
__global__ void k_classifier(const float* __restrict__ ht, const float* __restrict__ w,
                             const float* __restrict__ bias, float* __restrict__ out) {
    int b = blockIdx.x, o = blockIdx.y;
    const float4* hb = (const float4*)(ht + (size_t)b * 96 * GV);
    const float4* wo = (const float4*)(w + (size_t)o * 96 * GV);
    float acc = 0.f;
    for (int f = threadIdx.x; f < 96 * GV / 4; f += 256) {
        float4 a = hb[f], c4 = wo[f];
        acc += a.x * c4.x + a.y * c4.y + a.z * c4.z + a.w * c4.w;
    }
    #pragma unroll
    for (int off = 32; off > 0; off >>= 1) acc += __shfl_down(acc, off, 64);
    __shared__ float red[4];
    int lane = threadIdx.x & 63, wvv = threadIdx.x >> 6;
    if (lane == 0) red[wvv] = acc;
    __syncthreads();
    if (threadIdx.x == 0) out[b * 10 + o] = red[0] + red[1] + red[2] + red[3] + bias[o];
}

// ---------------------------------------------------------------------------
extern "C" void kernel_launch(void* const* d_in, const int* in_sizes, int n_in,
                              void* d_out, int out_size, void* d_ws, size_t ws_size,
                              hipStream_t stream) {
    const float* x = (const float*)d_in[0];
    const float* wts[7]; const float* gs[7]; const float* bs[7];
    for (int i = 0; i < 7; ++i) {
        wts[i] = (const float*)d_in[2 + 3 * i];
        gs[i]  = (const float*)d_in[3 + 3 * i];
        bs[i]  = (const float*)d_in[4 + 3 * i];
    }
    const float* clfw = (const float*)d_in[23];
    const float* clfb = (const float*)d_in[24];
    float* out = (float*)d_out;

    const int fin[7]  = {3, 96, 96, 96, 192, 192, 192};
    const int fout[7] = {96, 96, 96, 192, 192, 192, 96};
    int KdPad[7];
    for (int i = 0; i < 7; ++i) KdPad[i] = (fin[i] == 3) ? 32 : fin[i] * CHEB_K;

    // ---- workspace layout (floats) ----
    const size_t BIG = (size_t)M_TOT * 192;
    float* ws = (float*)d_ws;
    float* bufA = ws;
    float* bufB = ws + BIG;
    float* stats = ws + 2 * BIG;                 // 7 * 384 floats
    __hip_bfloat16* Wb = (__hip_bfloat16*)(stats + 7 * 384);
    size_t wbOff[7], wtot = 0;
    for (int i = 0; i < 7; ++i) { wbOff[i] = wtot; wtot += (size_t)fout[i] * KdPad[i]; }
    wtot = (wtot + 7) & ~(size_t)7;              // keep F 16B-aligned
    __hip_bfloat16* F = Wb + wtot;
    size_t usedBytes = (size_t)((char*)F - (char*)ws);
    size_t availBf16 = (ws_size > usedBytes) ? (ws_size - usedBytes) / 2 : 0;
    size_t Fneed = (size_t)M_TOT * 960;          // bf16 elems at nch=1
    int nch = 1;
    while (nch < 16 && Fneed / nch > availBf16) nch <<= 1;   // deterministic in ws_size

    hipMemsetAsync(stats, 0, 7 * 384 * sizeof(float), stream);
    for (int i = 0; i < 7; ++i) {
        int tot = fout[i] * KdPad[i];
        hipLaunchKernelGGL(k_convw, dim3((tot + 255) / 256), dim3(256), 0, stream,
                           wts[i], Wb + wbOff[i], fin[i], fout[i], KdPad[i]);
    }

    float* cur = nullptr;
    float* nxt = bufA;
    int Bc = BATCH / nch;                        // batches per chunk
    for (int li = 0; li < 7; ++li) {
        int Ci = fin[li], Co = fout[li];
        int CC = (li == 0) ? 3 : 8;
        int nchunkC = Ci / CC;
        const float* Xin = (li == 0) ? x : cur;
        const float* pst = (li == 0) ? stats : stats + (li - 1) * 384;  // unused if !useBN
        const float* pg  = (li == 0) ? gs[0] : gs[li - 1];
        const float* pb  = (li == 0) ? bs[0] : bs[li - 1];
        for (int ch = 0; ch < nch; ++ch) {
            int bOff = ch * Bc;
            hipLaunchKernelGGL(k_cheb_expand, dim3(nchunkC, Bc), dim3(512), 0, stream,
                               Xin, pst, pg, pb, F, Ci, CC, KdPad[li],
                               (li > 0) ? 1 : 0, (li == 0) ? 1 : 0, bOff);
            float* Yc = nxt + (size_t)bOff * GV * Co;
            dim3 gg(Bc * 8);                      // (Bc*1024)/128 blocks
            if (Co == 96)
                hipLaunchKernelGGL(k_gemm_bf16<6>, gg, dim3(256), 0, stream,
                                   F, Wb + wbOff[li], Yc, stats + li * 384, KdPad[li]);
            else
                hipLaunchKernelGGL(k_gemm_bf16<12>, gg, dim3(256), 0, stream,
                                   F, Wb + wbOff[li], Yc, stats + li * 384, KdPad[li]);
        }
        cur = nxt;
        nxt = (nxt == bufA) ? bufB : bufA;
    }
    // cur = Y6 [M,96]; apply BN+ReLU while transposing to [B,96,V] into nxt
    hipLaunchKernelGGL(k_bn_transpose_h, dim3((BATCH * 96 * GV + 255) / 256), dim3(256), 0, stream,
                       cur, stats + 6 * 384, gs[6], bs[6], nxt);
    hipLaunchKernelGGL(k_classifier, dim3(BATCH, 10), dim3(256), 0, stream, nxt, clfw, clfb, out);
}